// Round 7
// baseline (1068.075 us; speedup 1.0000x reference)
//
#include <hip/hip_runtime.h>
#include <math.h>

#define NN 100000
#define EE 800000
#define HH 12
#define FF 8
#define DD 96
#define NBLK_SCAN 98   // ceil(100000/1024)
#define WROW 104       // padded LDS row (bf16 elems)

typedef __bf16 bf16x8 __attribute__((ext_vector_type(8)));
typedef float  f32x4  __attribute__((ext_vector_type(4)));

static __device__ __forceinline__ unsigned short f2bf(float f) {
    unsigned u = __builtin_bit_cast(unsigned, f);
    u += 0x7fffu + ((u >> 16) & 1u);           // round-to-nearest-even
    return (unsigned short)(u >> 16);
}
static __device__ __forceinline__ unsigned packbf(float a, float b) {
    return (unsigned)f2bf(a) | ((unsigned)f2bf(b) << 16);
}

// ---------------- node scores + zero-init (fused) ----------------
__global__ __launch_bounds__(256) void k_scores(
    const float* __restrict__ x, const float* __restrict__ wsrc,
    const float* __restrict__ wtrg, float* __restrict__ s_src,
    float* __restrict__ s_trg, int* __restrict__ counts,
    int* __restrict__ chunks)
{
    int tid = blockIdx.x * 256 + threadIdx.x;
    if (tid < NN) counts[tid] = 0;
    if (tid < 128) chunks[tid] = 0;
    if (tid >= NN * HH) return;
    int h = tid % HH;
    int n = tid / HH;
    const float4* xp = (const float4*)(x + (size_t)n * DD + h * FF);
    float4 a = xp[0], b = xp[1];
    const float4* s4 = (const float4*)(wsrc + h * FF);
    const float4* t4 = (const float4*)(wtrg + h * FF);
    float4 sa = s4[0], sb = s4[1];
    float4 ta = t4[0], tb = t4[1];
    s_src[tid] = a.x*sa.x + a.y*sa.y + a.z*sa.z + a.w*sa.w
               + b.x*sb.x + b.y*sb.y + b.z*sb.z + b.w*sb.w;
    s_trg[tid] = a.x*ta.x + a.y*ta.y + a.z*ta.z + a.w*ta.w
               + b.x*tb.x + b.y*tb.y + b.z*tb.z + b.w*tb.w;
}

// ---------------- histogram: per-node counts + per-1024-chunk sums ----------------
__global__ __launch_bounds__(256) void k_hist(const int* __restrict__ ei,
                                              int* __restrict__ counts,
                                              int* __restrict__ chunks)
{
    int e = blockIdx.x * 256 + threadIdx.x;
    if (e >= EE) return;
    int t = ei[EE + e];
    atomicAdd(&counts[t], 1);
    atomicAdd(&chunks[t >> 10], 1);
}

// ---------------- single-kernel exclusive scan ----------------
// 98 blocks; each block scans the 98 chunk sums locally (no cross-block dep),
// takes its prefix, then scans its own 1024 counts -> offsets + cursor.
__global__ __launch_bounds__(256) void k_scan(const int* __restrict__ counts,
                                              const int* __restrict__ chunks,
                                              int* __restrict__ offsets,
                                              int* __restrict__ cursor)
{
    __shared__ int sc[128];
    __shared__ int sd[256];
    int t = threadIdx.x;
    if (t < 128) sc[t] = (t < NBLK_SCAN) ? chunks[t] : 0;
    __syncthreads();
    for (int off = 1; off < 128; off <<= 1) {
        int u = (t < 128 && t >= off) ? sc[t - off] : 0;
        __syncthreads();
        if (t < 128) sc[t] += u;
        __syncthreads();
    }
    int bof = (blockIdx.x == 0) ? 0 : sc[blockIdx.x - 1];

    int base = blockIdx.x * 1024 + t * 4;
    int c[4];
    int s = 0;
    #pragma unroll
    for (int j = 0; j < 4; ++j) {
        int i = base + j;
        c[j] = (i < NN) ? counts[i] : 0;
        s += c[j];
    }
    sd[t] = s;
    __syncthreads();
    for (int off = 1; off < 256; off <<= 1) {
        int u = (t >= off) ? sd[t - off] : 0;
        __syncthreads();
        sd[t] += u;
        __syncthreads();
    }
    int run = bof + ((t == 0) ? 0 : sd[t - 1]);
    #pragma unroll
    for (int j = 0; j < 4; ++j) {
        int i = base + j;
        if (i < NN) { offsets[i] = run; cursor[i] = run; }
        run += c[j];
    }
}

__global__ __launch_bounds__(256) void k_scatter(const int* __restrict__ ei,
                                                 int* __restrict__ cursor,
                                                 int* __restrict__ esrc)
{
    int e = blockIdx.x * 256 + threadIdx.x;
    if (e >= EE) return;
    int s = ei[e];
    int t = ei[EE + e];
    int pos = atomicAdd(&cursor[t], 1);
    esrc[pos] = s;
}

// ---------------- fused aggregate + softmax + RMS norm + projection + residual ----
// block = 768 threads (12 waves) = 64 nodes x 12 heads; grid = ceil(NN/64).
// Phase 1: thread (ln,h) aggregates its node's incoming edges (CSR), RMS-norms,
//          writes bf16 y-row piece straight to LDS (y never touches HBM).
// Phase 2: 12 waves x 2 output tiles: 64x96 @ 96x96 bf16 MFMA vs W staged in LDS.
// Phase 3: acc -> f32 LDS bounce -> coalesced x-residual add + store.
__global__ __launch_bounds__(768) void k_aggout(
    const float* __restrict__ x, const float* __restrict__ s_src,
    const float* __restrict__ s_trg, const int* __restrict__ offsets,
    const int* __restrict__ counts, const int* __restrict__ esrc,
    const float* __restrict__ lnw, const float* __restrict__ w,
    float* __restrict__ out)
{
    __shared__ char lds_raw[(96 + 64) * WROW * 2];   // 33280 B, reused as f32 fb later
    __shared__ float nsq[64];
    unsigned short* wl = (unsigned short*)lds_raw;                  // [96][WROW]
    unsigned short* yl = ((unsigned short*)lds_raw) + 96 * WROW;    // [64][WROW]
    int t    = threadIdx.x;
    int tile = blockIdx.x * 64;
    int nrem = NN - tile;          // last block: 32

    // stage W (9216 floats) as bf16, coalesced; zero nsq
    if (t < 64) nsq[t] = 0.f;
    #pragma unroll
    for (int i = 0; i < 3; ++i) {
        int lin = t * 4 + i * 3072;
        int r = lin / 96, c = lin - (lin / 96) * 96;
        float4 v = *(const float4*)(w + lin);
        unsigned* p = (unsigned*)(wl + r * WROW + c);
        p[0] = packbf(v.x, v.y); p[1] = packbf(v.z, v.w);
    }
    __syncthreads();

    // ---- phase 1: aggregation (node ln, head h) ----
    {
        int ln = t / HH;
        int h  = t - ln * HH;
        int n  = tile + ln;
        bool valid = (n < NN);
        float st = 0.f; int beg = 0, cnt = 0;
        if (valid) {
            st  = s_trg[n * HH + h];
            beg = offsets[n];
            cnt = counts[n];
        }
        float denom = 0.f;
        float4 aa = {0.f, 0.f, 0.f, 0.f};
        float4 ab = {0.f, 0.f, 0.f, 0.f};
        int s_cur = (cnt > 0) ? esrc[beg] : 0;
        for (int k = 0; k < cnt; ++k) {
            int s_nxt = (k + 1 < cnt) ? esrc[beg + k + 1] : 0;   // prefetch
            float sc = s_src[s_cur * HH + h] + st;
            sc = (sc >= 0.f) ? sc : 0.2f * sc;
            float ex = __expf(sc);
            denom += ex;
            const float4* xp = (const float4*)(x + (size_t)s_cur * DD + h * FF);
            float4 a = xp[0], b = xp[1];
            aa.x += a.x * ex; aa.y += a.y * ex; aa.z += a.z * ex; aa.w += a.w * ex;
            ab.x += b.x * ex; ab.y += b.y * ex; ab.z += b.z * ex; ab.w += b.w * ex;
            s_cur = s_nxt;
        }
        float inv = 1.f / (denom + 1e-16f);
        float yp[8];
        yp[0] = aa.x * inv; yp[1] = aa.y * inv; yp[2] = aa.z * inv; yp[3] = aa.w * inv;
        yp[4] = ab.x * inv; yp[5] = ab.y * inv; yp[6] = ab.z * inv; yp[7] = ab.w * inv;
        float ss = 0.f;
        #pragma unroll
        for (int j = 0; j < 8; ++j) ss += yp[j] * yp[j];
        atomicAdd(&nsq[ln], ss);
        __syncthreads();
        float scale = rsqrtf(nsq[ln] * (1.f / 96.f) + 1e-6f);
        const float4* lw = (const float4*)(lnw + h * FF);
        float4 w1 = lw[0], w2 = lw[1];
        unsigned* yo = (unsigned*)(yl + ln * WROW + h * FF);
        yo[0] = packbf(yp[0] * scale * w1.x, yp[1] * scale * w1.y);
        yo[1] = packbf(yp[2] * scale * w1.z, yp[3] * scale * w1.w);
        yo[2] = packbf(yp[4] * scale * w2.x, yp[5] * scale * w2.y);
        yo[3] = packbf(yp[6] * scale * w2.z, yp[7] * scale * w2.w);
    }
    __syncthreads();

    // ---- phase 2: MFMA projection. 24 output 16x16 tiles; wave wv owns 2 ----
    int wv = t >> 6;
    int l  = t & 63;
    int tt0 = wv * 2;              // both tiles share the row-tile rt
    int rt  = tt0 / 6;
    int ct0 = tt0 - rt * 6;
    int kchunk = (l >> 4) * 8;
    int arow = rt * 16 + (l & 15);
    f32x4 acc0 = {}, acc1 = {};
    #pragma unroll
    for (int s = 0; s < 3; ++s) {
        bf16x8 af = *(const bf16x8*)(yl + arow * WROW + s * 32 + kchunk);
        bf16x8 b0 = *(const bf16x8*)(wl + ((ct0 + 0) * 16 + (l & 15)) * WROW + s * 32 + kchunk);
        bf16x8 b1 = *(const bf16x8*)(wl + ((ct0 + 1) * 16 + (l & 15)) * WROW + s * 32 + kchunk);
        acc0 = __builtin_amdgcn_mfma_f32_16x16x32_bf16(af, b0, acc0, 0, 0, 0);
        acc1 = __builtin_amdgcn_mfma_f32_16x16x32_bf16(af, b1, acc1, 0, 0, 0);
    }
    __syncthreads();

    // ---- phase 3: bounce to f32 LDS, coalesced residual add + store ----
    float* fb = (float*)lds_raw;   // [64][97] = 24832 B, overwrites wl/yl
    {
        int row = rt * 16 + (l >> 4) * 4;
        int col = ct0 * 16 + (l & 15);
        #pragma unroll
        for (int r = 0; r < 4; ++r) {
            fb[(row + r) * 97 + col]      = acc0[r];
            fb[(row + r) * 97 + col + 16] = acc1[r];
        }
    }
    __syncthreads();
    #pragma unroll
    for (int i = 0; i < 2; ++i) {
        int lin = t * 4 + i * 3072;
        int r = lin / 96, c = lin - (lin / 96) * 96;
        if (r < nrem) {
            float4 xv = *(const float4*)(x + (size_t)tile * DD + lin);
            float4 o;
            o.x = xv.x + fb[r * 97 + c + 0];
            o.y = xv.y + fb[r * 97 + c + 1];
            o.z = xv.z + fb[r * 97 + c + 2];
            o.w = xv.w + fb[r * 97 + c + 3];
            *(float4*)(out + (size_t)tile * DD + lin) = o;
        }
    }
}

extern "C" void kernel_launch(void* const* d_in, const int* in_sizes, int n_in,
                              void* d_out, int out_size, void* d_ws, size_t ws_size,
                              hipStream_t stream)
{
    const float* x    = (const float*)d_in[0];
    const int*   ei   = (const int*)d_in[1];
    const float* wprj = (const float*)d_in[2];
    const float* wsrc = (const float*)d_in[3];
    const float* wtrg = (const float*)d_in[4];
    const float* lnw  = (const float*)d_in[5];
    float* out = (float*)d_out;

    float* s_src  = (float*)d_ws;
    float* s_trg  = s_src + NN * HH;
    int*   counts = (int*)(s_trg + NN * HH);
    int*   offs   = counts + NN;
    int*   cursor = offs + NN;
    int*   chunks = cursor + NN;
    int*   esrc   = chunks + 128;

    k_scores<<<(NN * HH + 255) / 256, 256, 0, stream>>>(x, wsrc, wtrg, s_src, s_trg, counts, chunks);
    k_hist<<<(EE + 255) / 256, 256, 0, stream>>>(ei, counts, chunks);
    k_scan<<<NBLK_SCAN, 256, 0, stream>>>(counts, chunks, offs, cursor);
    k_scatter<<<(EE + 255) / 256, 256, 0, stream>>>(ei, cursor, esrc);
    k_aggout<<<(NN + 63) / 64, 768, 0, stream>>>(x, s_src, s_trg, offs, counts, esrc, lnw, wprj, out);
}

// Round 8
// 269.556 us; speedup vs baseline: 3.9623x; 3.9623x over previous
//
#include <hip/hip_runtime.h>
#include <math.h>

#define NN 100000
#define EE 800000
#define HH 12
#define FF 8
#define DD 96
#define NBLK_SCAN 98   // ceil(100000/1024)
#define WROW 104       // padded LDS row (bf16 elems)

typedef __bf16 bf16x8 __attribute__((ext_vector_type(8)));
typedef float  f32x4  __attribute__((ext_vector_type(4)));

static __device__ __forceinline__ unsigned short f2bf(float f) {
    unsigned u = __builtin_bit_cast(unsigned, f);
    u += 0x7fffu + ((u >> 16) & 1u);           // round-to-nearest-even
    return (unsigned short)(u >> 16);
}
static __device__ __forceinline__ unsigned packbf(float a, float b) {
    return (unsigned)f2bf(a) | ((unsigned)f2bf(b) << 16);
}

// ---------------- node scores + counts zero-init (fused) ----------------
__global__ __launch_bounds__(256) void k_scores(
    const float* __restrict__ x, const float* __restrict__ wsrc,
    const float* __restrict__ wtrg, float* __restrict__ s_src,
    float* __restrict__ s_trg, int* __restrict__ counts)
{
    int tid = blockIdx.x * 256 + threadIdx.x;
    if (tid < NN) counts[tid] = 0;
    if (tid >= NN * HH) return;
    int h = tid % HH;
    int n = tid / HH;
    const float4* xp = (const float4*)(x + (size_t)n * DD + h * FF);
    float4 a = xp[0], b = xp[1];
    const float4* s4 = (const float4*)(wsrc + h * FF);
    const float4* t4 = (const float4*)(wtrg + h * FF);
    float4 sa = s4[0], sb = s4[1];
    float4 ta = t4[0], tb = t4[1];
    s_src[tid] = a.x*sa.x + a.y*sa.y + a.z*sa.z + a.w*sa.w
               + b.x*sb.x + b.y*sb.y + b.z*sb.z + b.w*sb.w;
    s_trg[tid] = a.x*ta.x + a.y*ta.y + a.z*ta.z + a.w*ta.w
               + b.x*tb.x + b.y*tb.y + b.z*tb.z + b.w*tb.w;
}

// ---------------- histogram: per-node counts ONLY ----------------
// (R7 lesson: a second atomic onto 98 chunk counters = 800k atomics on ~2
//  cache lines -> 834 µs of serialization. Chunk sums are now reduced from
//  counts in k_chunks instead.)
__global__ __launch_bounds__(256) void k_hist(const int* __restrict__ ei,
                                              int* __restrict__ counts)
{
    int e = blockIdx.x * 256 + threadIdx.x;
    if (e >= EE) return;
    int t = ei[EE + e];
    atomicAdd(&counts[t], 1);
}

// ---------------- per-1024-chunk sums by tree reduction ----------------
__global__ __launch_bounds__(256) void k_chunks(const int* __restrict__ counts,
                                                int* __restrict__ chunks)
{
    __shared__ int sd[256];
    int t = threadIdx.x;
    int base = blockIdx.x * 1024 + t * 4;
    int s = 0;
    #pragma unroll
    for (int j = 0; j < 4; ++j) {
        int i = base + j;
        s += (i < NN) ? counts[i] : 0;
    }
    sd[t] = s;
    __syncthreads();
    for (int off = 128; off > 0; off >>= 1) {
        if (t < off) sd[t] += sd[t + off];
        __syncthreads();
    }
    if (t == 0) chunks[blockIdx.x] = sd[0];
}

// ---------------- single-kernel exclusive scan ----------------
// 98 blocks; each block scans the 98 chunk sums locally (no cross-block dep),
// takes its prefix, then scans its own 1024 counts -> offsets + cursor.
__global__ __launch_bounds__(256) void k_scan(const int* __restrict__ counts,
                                              const int* __restrict__ chunks,
                                              int* __restrict__ offsets,
                                              int* __restrict__ cursor)
{
    __shared__ int sc[128];
    __shared__ int sd[256];
    int t = threadIdx.x;
    if (t < 128) sc[t] = (t < NBLK_SCAN) ? chunks[t] : 0;
    __syncthreads();
    for (int off = 1; off < 128; off <<= 1) {
        int u = (t < 128 && t >= off) ? sc[t - off] : 0;
        __syncthreads();
        if (t < 128) sc[t] += u;
        __syncthreads();
    }
    int bof = (blockIdx.x == 0) ? 0 : sc[blockIdx.x - 1];

    int base = blockIdx.x * 1024 + t * 4;
    int c[4];
    int s = 0;
    #pragma unroll
    for (int j = 0; j < 4; ++j) {
        int i = base + j;
        c[j] = (i < NN) ? counts[i] : 0;
        s += c[j];
    }
    sd[t] = s;
    __syncthreads();
    for (int off = 1; off < 256; off <<= 1) {
        int u = (t >= off) ? sd[t - off] : 0;
        __syncthreads();
        sd[t] += u;
        __syncthreads();
    }
    int run = bof + ((t == 0) ? 0 : sd[t - 1]);
    #pragma unroll
    for (int j = 0; j < 4; ++j) {
        int i = base + j;
        if (i < NN) { offsets[i] = run; cursor[i] = run; }
        run += c[j];
    }
}

__global__ __launch_bounds__(256) void k_scatter(const int* __restrict__ ei,
                                                 int* __restrict__ cursor,
                                                 int* __restrict__ esrc)
{
    int e = blockIdx.x * 256 + threadIdx.x;
    if (e >= EE) return;
    int s = ei[e];
    int t = ei[EE + e];
    int pos = atomicAdd(&cursor[t], 1);
    esrc[pos] = s;
}

// ---------------- fused aggregate + softmax + RMS norm + projection + residual ----
// block = 768 threads (12 waves) = 64 nodes x 12 heads; grid = ceil(NN/64).
// Phase 1: thread (ln,h) aggregates its node's incoming edges (CSR), RMS-norms,
//          writes bf16 y-row piece straight to LDS (y never touches HBM).
// Phase 2: 12 waves x 2 output tiles: 64x96 @ 96x96 bf16 MFMA vs W staged in LDS.
// Phase 3: acc -> f32 LDS bounce -> coalesced x-residual add + store.
__global__ __launch_bounds__(768) void k_aggout(
    const float* __restrict__ x, const float* __restrict__ s_src,
    const float* __restrict__ s_trg, const int* __restrict__ offsets,
    const int* __restrict__ counts, const int* __restrict__ esrc,
    const float* __restrict__ lnw, const float* __restrict__ w,
    float* __restrict__ out)
{
    __shared__ char lds_raw[(96 + 64) * WROW * 2];   // 33280 B, reused as f32 fb later
    __shared__ float nsq[64];
    unsigned short* wl = (unsigned short*)lds_raw;                  // [96][WROW]
    unsigned short* yl = ((unsigned short*)lds_raw) + 96 * WROW;    // [64][WROW]
    int t    = threadIdx.x;
    int tile = blockIdx.x * 64;
    int nrem = NN - tile;          // last block: 32

    // stage W (9216 floats) as bf16, coalesced; zero nsq
    if (t < 64) nsq[t] = 0.f;
    #pragma unroll
    for (int i = 0; i < 3; ++i) {
        int lin = t * 4 + i * 3072;
        int r = lin / 96, c = lin - (lin / 96) * 96;
        float4 v = *(const float4*)(w + lin);
        unsigned* p = (unsigned*)(wl + r * WROW + c);
        p[0] = packbf(v.x, v.y); p[1] = packbf(v.z, v.w);
    }
    __syncthreads();

    // ---- phase 1: aggregation (node ln, head h) ----
    {
        int ln = t / HH;
        int h  = t - ln * HH;
        int n  = tile + ln;
        bool valid = (n < NN);
        float st = 0.f; int beg = 0, cnt = 0;
        if (valid) {
            st  = s_trg[n * HH + h];
            beg = offsets[n];
            cnt = counts[n];
        }
        float denom = 0.f;
        float4 aa = {0.f, 0.f, 0.f, 0.f};
        float4 ab = {0.f, 0.f, 0.f, 0.f};
        int s_cur = (cnt > 0) ? esrc[beg] : 0;
        for (int k = 0; k < cnt; ++k) {
            int s_nxt = (k + 1 < cnt) ? esrc[beg + k + 1] : 0;   // prefetch
            float sc = s_src[s_cur * HH + h] + st;
            sc = (sc >= 0.f) ? sc : 0.2f * sc;
            float ex = __expf(sc);
            denom += ex;
            const float4* xp = (const float4*)(x + (size_t)s_cur * DD + h * FF);
            float4 a = xp[0], b = xp[1];
            aa.x += a.x * ex; aa.y += a.y * ex; aa.z += a.z * ex; aa.w += a.w * ex;
            ab.x += b.x * ex; ab.y += b.y * ex; ab.z += b.z * ex; ab.w += b.w * ex;
            s_cur = s_nxt;
        }
        float inv = 1.f / (denom + 1e-16f);
        float yp[8];
        yp[0] = aa.x * inv; yp[1] = aa.y * inv; yp[2] = aa.z * inv; yp[3] = aa.w * inv;
        yp[4] = ab.x * inv; yp[5] = ab.y * inv; yp[6] = ab.z * inv; yp[7] = ab.w * inv;
        float ss = 0.f;
        #pragma unroll
        for (int j = 0; j < 8; ++j) ss += yp[j] * yp[j];
        atomicAdd(&nsq[ln], ss);
        __syncthreads();
        float scale = rsqrtf(nsq[ln] * (1.f / 96.f) + 1e-6f);
        const float4* lw = (const float4*)(lnw + h * FF);
        float4 w1 = lw[0], w2 = lw[1];
        unsigned* yo = (unsigned*)(yl + ln * WROW + h * FF);
        yo[0] = packbf(yp[0] * scale * w1.x, yp[1] * scale * w1.y);
        yo[1] = packbf(yp[2] * scale * w1.z, yp[3] * scale * w1.w);
        yo[2] = packbf(yp[4] * scale * w2.x, yp[5] * scale * w2.y);
        yo[3] = packbf(yp[6] * scale * w2.z, yp[7] * scale * w2.w);
    }
    __syncthreads();

    // ---- phase 2: MFMA projection. 24 output 16x16 tiles; wave wv owns 2 ----
    int wv = t >> 6;
    int l  = t & 63;
    int tt0 = wv * 2;              // both tiles share the row-tile rt
    int rt  = tt0 / 6;
    int ct0 = tt0 - rt * 6;
    int kchunk = (l >> 4) * 8;
    int arow = rt * 16 + (l & 15);
    f32x4 acc0 = {}, acc1 = {};
    #pragma unroll
    for (int s = 0; s < 3; ++s) {
        bf16x8 af = *(const bf16x8*)(yl + arow * WROW + s * 32 + kchunk);
        bf16x8 b0 = *(const bf16x8*)(wl + ((ct0 + 0) * 16 + (l & 15)) * WROW + s * 32 + kchunk);
        bf16x8 b1 = *(const bf16x8*)(wl + ((ct0 + 1) * 16 + (l & 15)) * WROW + s * 32 + kchunk);
        acc0 = __builtin_amdgcn_mfma_f32_16x16x32_bf16(af, b0, acc0, 0, 0, 0);
        acc1 = __builtin_amdgcn_mfma_f32_16x16x32_bf16(af, b1, acc1, 0, 0, 0);
    }
    __syncthreads();

    // ---- phase 3: bounce to f32 LDS, coalesced residual add + store ----
    float* fb = (float*)lds_raw;   // [64][97] = 24832 B, overwrites wl/yl
    {
        int row = rt * 16 + (l >> 4) * 4;
        int col = ct0 * 16 + (l & 15);
        #pragma unroll
        for (int r = 0; r < 4; ++r) {
            fb[(row + r) * 97 + col]      = acc0[r];
            fb[(row + r) * 97 + col + 16] = acc1[r];
        }
    }
    __syncthreads();
    #pragma unroll
    for (int i = 0; i < 2; ++i) {
        int lin = t * 4 + i * 3072;
        int r = lin / 96, c = lin - (lin / 96) * 96;
        if (r < nrem) {
            float4 xv = *(const float4*)(x + (size_t)tile * DD + lin);
            float4 o;
            o.x = xv.x + fb[r * 97 + c + 0];
            o.y = xv.y + fb[r * 97 + c + 1];
            o.z = xv.z + fb[r * 97 + c + 2];
            o.w = xv.w + fb[r * 97 + c + 3];
            *(float4*)(out + (size_t)tile * DD + lin) = o;
        }
    }
}

extern "C" void kernel_launch(void* const* d_in, const int* in_sizes, int n_in,
                              void* d_out, int out_size, void* d_ws, size_t ws_size,
                              hipStream_t stream)
{
    const float* x    = (const float*)d_in[0];
    const int*   ei   = (const int*)d_in[1];
    const float* wprj = (const float*)d_in[2];
    const float* wsrc = (const float*)d_in[3];
    const float* wtrg = (const float*)d_in[4];
    const float* lnw  = (const float*)d_in[5];
    float* out = (float*)d_out;

    float* s_src  = (float*)d_ws;
    float* s_trg  = s_src + NN * HH;
    int*   counts = (int*)(s_trg + NN * HH);
    int*   offs   = counts + NN;
    int*   cursor = offs + NN;
    int*   chunks = cursor + NN;
    int*   esrc   = chunks + 128;

    k_scores<<<(NN * HH + 255) / 256, 256, 0, stream>>>(x, wsrc, wtrg, s_src, s_trg, counts);
    k_hist<<<(EE + 255) / 256, 256, 0, stream>>>(ei, counts);
    k_chunks<<<NBLK_SCAN, 256, 0, stream>>>(counts, chunks);
    k_scan<<<NBLK_SCAN, 256, 0, stream>>>(counts, chunks, offs, cursor);
    k_scatter<<<(EE + 255) / 256, 256, 0, stream>>>(ei, cursor, esrc);
    k_aggout<<<(NN + 63) / 64, 768, 0, stream>>>(x, s_src, s_trg, offs, counts, esrc, lnw, wprj, out);
}

// Round 9
// 221.095 us; speedup vs baseline: 4.8308x; 1.2192x over previous
//
#include <hip/hip_runtime.h>
#include <math.h>

#define NN 100000
#define EE 800000
#define HH 12
#define FF 8
#define DD 96
#define NBLK_SCAN 98   // ceil(100000/1024)
#define WROW 104       // padded LDS row (bf16 elems)

typedef __bf16 bf16x8 __attribute__((ext_vector_type(8)));
typedef float  f32x4  __attribute__((ext_vector_type(4)));

static __device__ __forceinline__ unsigned short f2bf(float f) {
    unsigned u = __builtin_bit_cast(unsigned, f);
    u += 0x7fffu + ((u >> 16) & 1u);           // round-to-nearest-even
    return (unsigned short)(u >> 16);
}
static __device__ __forceinline__ unsigned packbf(float a, float b) {
    return (unsigned)f2bf(a) | ((unsigned)f2bf(b) << 16);
}
static __device__ __forceinline__ float bflo(unsigned u) {
    return __builtin_bit_cast(float, u << 16);
}
static __device__ __forceinline__ float bfhi(unsigned u) {
    return __builtin_bit_cast(float, u & 0xffff0000u);
}

// ------- node scores + counts zero-init + x->bf16 mirror (fused) -------
__global__ __launch_bounds__(256) void k_scores(
    const float* __restrict__ x, const float* __restrict__ wsrc,
    const float* __restrict__ wtrg, float* __restrict__ s_src,
    float* __restrict__ s_trg, int* __restrict__ counts,
    unsigned short* __restrict__ xb)
{
    int tid = blockIdx.x * 256 + threadIdx.x;
    if (tid < NN) counts[tid] = 0;
    if (tid >= NN * HH) return;
    int h = tid % HH;
    int n = tid / HH;
    const float4* xp = (const float4*)(x + (size_t)n * DD + h * FF);
    float4 a = xp[0], b = xp[1];
    // bf16 mirror of x for the gather in k_aggout (halves gather bytes)
    unsigned* xo = (unsigned*)(xb + (size_t)n * DD + h * FF);
    xo[0] = packbf(a.x, a.y); xo[1] = packbf(a.z, a.w);
    xo[2] = packbf(b.x, b.y); xo[3] = packbf(b.z, b.w);
    const float4* s4 = (const float4*)(wsrc + h * FF);
    const float4* t4 = (const float4*)(wtrg + h * FF);
    float4 sa = s4[0], sb = s4[1];
    float4 ta = t4[0], tb = t4[1];
    s_src[tid] = a.x*sa.x + a.y*sa.y + a.z*sa.z + a.w*sa.w
               + b.x*sb.x + b.y*sb.y + b.z*sb.z + b.w*sb.w;
    s_trg[tid] = a.x*ta.x + a.y*ta.y + a.z*ta.z + a.w*ta.w
               + b.x*tb.x + b.y*tb.y + b.z*tb.z + b.w*tb.w;
}

// ------- histogram + per-edge rank (kills the scatter atomic) -------
__global__ __launch_bounds__(256) void k_hist(const int* __restrict__ ei,
                                              int* __restrict__ counts,
                                              int* __restrict__ rank)
{
    int e = blockIdx.x * 256 + threadIdx.x;
    if (e >= EE) return;
    int t = ei[EE + e];
    rank[e] = atomicAdd(&counts[t], 1);   // coalesced 4B write of the old value
}

// ------- per-1024-chunk sums by tree reduction (R7 lesson: no chunk atomics) ---
__global__ __launch_bounds__(256) void k_chunks(const int* __restrict__ counts,
                                                int* __restrict__ chunks)
{
    __shared__ int sd[256];
    int t = threadIdx.x;
    int base = blockIdx.x * 1024 + t * 4;
    int s = 0;
    #pragma unroll
    for (int j = 0; j < 4; ++j) {
        int i = base + j;
        s += (i < NN) ? counts[i] : 0;
    }
    sd[t] = s;
    __syncthreads();
    for (int off = 128; off > 0; off >>= 1) {
        if (t < off) sd[t] += sd[t + off];
        __syncthreads();
    }
    if (t == 0) chunks[blockIdx.x] = sd[0];
}

// ------- single-kernel exclusive scan -> offsets -------
__global__ __launch_bounds__(256) void k_scan(const int* __restrict__ counts,
                                              const int* __restrict__ chunks,
                                              int* __restrict__ offsets)
{
    __shared__ int sc[128];
    __shared__ int sd[256];
    int t = threadIdx.x;
    if (t < 128) sc[t] = (t < NBLK_SCAN) ? chunks[t] : 0;
    __syncthreads();
    for (int off = 1; off < 128; off <<= 1) {
        int u = (t < 128 && t >= off) ? sc[t - off] : 0;
        __syncthreads();
        if (t < 128) sc[t] += u;
        __syncthreads();
    }
    int bof = (blockIdx.x == 0) ? 0 : sc[blockIdx.x - 1];

    int base = blockIdx.x * 1024 + t * 4;
    int c[4];
    int s = 0;
    #pragma unroll
    for (int j = 0; j < 4; ++j) {
        int i = base + j;
        c[j] = (i < NN) ? counts[i] : 0;
        s += c[j];
    }
    sd[t] = s;
    __syncthreads();
    for (int off = 1; off < 256; off <<= 1) {
        int u = (t >= off) ? sd[t - off] : 0;
        __syncthreads();
        sd[t] += u;
        __syncthreads();
    }
    int run = bof + ((t == 0) ? 0 : sd[t - 1]);
    #pragma unroll
    for (int j = 0; j < 4; ++j) {
        int i = base + j;
        if (i < NN) offsets[i] = run;
        run += c[j];
    }
}

// ------- scatter: no atomics, rank precomputed -------
__global__ __launch_bounds__(256) void k_scatter(const int* __restrict__ ei,
                                                 const int* __restrict__ offsets,
                                                 const int* __restrict__ rank,
                                                 int* __restrict__ esrc)
{
    int e = blockIdx.x * 256 + threadIdx.x;
    if (e >= EE) return;
    int s = ei[e];
    int t = ei[EE + e];
    esrc[offsets[t] + rank[e]] = s;
}

// ---- fused aggregate + softmax + RMS norm + projection + residual ----
// block = 768 threads (12 waves) = 64 nodes x 12 heads; grid = ceil(NN/64).
// Phase 1: thread (ln,h) aggregates its node's incoming edges (CSR) gathering
//          bf16 x rows (16B/thread), RMS-norms, writes bf16 y to LDS.
// Phase 2: 12 waves x 2 output tiles: 64x96 @ 96x96 bf16 MFMA vs W in LDS.
// Phase 3: acc -> f32 LDS bounce -> coalesced x-residual add + store.
__global__ __launch_bounds__(768) void k_aggout(
    const float* __restrict__ x, const unsigned short* __restrict__ xb,
    const float* __restrict__ s_src, const float* __restrict__ s_trg,
    const int* __restrict__ offsets, const int* __restrict__ counts,
    const int* __restrict__ esrc, const float* __restrict__ lnw,
    const float* __restrict__ w, float* __restrict__ out)
{
    __shared__ char lds_raw[(96 + 64) * WROW * 2];   // 33280 B, reused as f32 fb later
    __shared__ float nsq[64];
    unsigned short* wl = (unsigned short*)lds_raw;                  // [96][WROW]
    unsigned short* yl = ((unsigned short*)lds_raw) + 96 * WROW;    // [64][WROW]
    int t    = threadIdx.x;
    int tile = blockIdx.x * 64;
    int nrem = NN - tile;          // last block: 32

    // stage W (9216 floats) as bf16, coalesced; zero nsq
    if (t < 64) nsq[t] = 0.f;
    #pragma unroll
    for (int i = 0; i < 3; ++i) {
        int lin = t * 4 + i * 3072;
        int r = lin / 96, c = lin - (lin / 96) * 96;
        float4 v = *(const float4*)(w + lin);
        unsigned* p = (unsigned*)(wl + r * WROW + c);
        p[0] = packbf(v.x, v.y); p[1] = packbf(v.z, v.w);
    }
    __syncthreads();

    // ---- phase 1: aggregation (node ln, head h), bf16 x gather ----
    {
        int ln = t / HH;
        int h  = t - ln * HH;
        int n  = tile + ln;
        bool valid = (n < NN);
        float st = 0.f; int beg = 0, cnt = 0;
        if (valid) {
            st  = s_trg[n * HH + h];
            beg = offsets[n];
            cnt = counts[n];
        }
        float denom = 0.f;
        float acc[8] = {0.f, 0.f, 0.f, 0.f, 0.f, 0.f, 0.f, 0.f};
        int s_cur = (cnt > 0) ? esrc[beg] : 0;
        for (int k = 0; k < cnt; ++k) {
            int s_nxt = (k + 1 < cnt) ? esrc[beg + k + 1] : 0;   // prefetch
            float sc = s_src[s_cur * HH + h] + st;
            sc = (sc >= 0.f) ? sc : 0.2f * sc;
            float ex = __expf(sc);
            denom += ex;
            uint4 q = *(const uint4*)(xb + (size_t)s_cur * DD + h * FF);
            acc[0] += bflo(q.x) * ex; acc[1] += bfhi(q.x) * ex;
            acc[2] += bflo(q.y) * ex; acc[3] += bfhi(q.y) * ex;
            acc[4] += bflo(q.z) * ex; acc[5] += bfhi(q.z) * ex;
            acc[6] += bflo(q.w) * ex; acc[7] += bfhi(q.w) * ex;
            s_cur = s_nxt;
        }
        float inv = 1.f / (denom + 1e-16f);
        float yp[8];
        #pragma unroll
        for (int j = 0; j < 8; ++j) yp[j] = acc[j] * inv;
        float ss = 0.f;
        #pragma unroll
        for (int j = 0; j < 8; ++j) ss += yp[j] * yp[j];
        atomicAdd(&nsq[ln], ss);
        __syncthreads();
        float scale = rsqrtf(nsq[ln] * (1.f / 96.f) + 1e-6f);
        const float4* lw = (const float4*)(lnw + h * FF);
        float4 w1 = lw[0], w2 = lw[1];
        unsigned* yo = (unsigned*)(yl + ln * WROW + h * FF);
        yo[0] = packbf(yp[0] * scale * w1.x, yp[1] * scale * w1.y);
        yo[1] = packbf(yp[2] * scale * w1.z, yp[3] * scale * w1.w);
        yo[2] = packbf(yp[4] * scale * w2.x, yp[5] * scale * w2.y);
        yo[3] = packbf(yp[6] * scale * w2.z, yp[7] * scale * w2.w);
    }
    __syncthreads();

    // ---- phase 2: MFMA projection. 24 output 16x16 tiles; wave wv owns 2 ----
    int wv = t >> 6;
    int l  = t & 63;
    int tt0 = wv * 2;              // both tiles share the row-tile rt
    int rt  = tt0 / 6;
    int ct0 = tt0 - rt * 6;
    int kchunk = (l >> 4) * 8;
    int arow = rt * 16 + (l & 15);
    f32x4 acc0 = {}, acc1 = {};
    #pragma unroll
    for (int s = 0; s < 3; ++s) {
        bf16x8 af = *(const bf16x8*)(yl + arow * WROW + s * 32 + kchunk);
        bf16x8 b0 = *(const bf16x8*)(wl + ((ct0 + 0) * 16 + (l & 15)) * WROW + s * 32 + kchunk);
        bf16x8 b1 = *(const bf16x8*)(wl + ((ct0 + 1) * 16 + (l & 15)) * WROW + s * 32 + kchunk);
        acc0 = __builtin_amdgcn_mfma_f32_16x16x32_bf16(af, b0, acc0, 0, 0, 0);
        acc1 = __builtin_amdgcn_mfma_f32_16x16x32_bf16(af, b1, acc1, 0, 0, 0);
    }
    __syncthreads();

    // ---- phase 3: bounce to f32 LDS, coalesced residual add + store ----
    float* fb = (float*)lds_raw;   // [64][97] = 24832 B, overwrites wl/yl
    {
        int row = rt * 16 + (l >> 4) * 4;
        int col = ct0 * 16 + (l & 15);
        #pragma unroll
        for (int r = 0; r < 4; ++r) {
            fb[(row + r) * 97 + col]      = acc0[r];
            fb[(row + r) * 97 + col + 16] = acc1[r];
        }
    }
    __syncthreads();
    #pragma unroll
    for (int i = 0; i < 2; ++i) {
        int lin = t * 4 + i * 3072;
        int r = lin / 96, c = lin - (lin / 96) * 96;
        if (r < nrem) {
            float4 xv = *(const float4*)(x + (size_t)tile * DD + lin);
            float4 o;
            o.x = xv.x + fb[r * 97 + c + 0];
            o.y = xv.y + fb[r * 97 + c + 1];
            o.z = xv.z + fb[r * 97 + c + 2];
            o.w = xv.w + fb[r * 97 + c + 3];
            *(float4*)(out + (size_t)tile * DD + lin) = o;
        }
    }
}

extern "C" void kernel_launch(void* const* d_in, const int* in_sizes, int n_in,
                              void* d_out, int out_size, void* d_ws, size_t ws_size,
                              hipStream_t stream)
{
    const float* x    = (const float*)d_in[0];
    const int*   ei   = (const int*)d_in[1];
    const float* wprj = (const float*)d_in[2];
    const float* wsrc = (const float*)d_in[3];
    const float* wtrg = (const float*)d_in[4];
    const float* lnw  = (const float*)d_in[5];
    float* out = (float*)d_out;

    float* s_src  = (float*)d_ws;
    float* s_trg  = s_src + NN * HH;
    int*   counts = (int*)(s_trg + NN * HH);
    int*   offs   = counts + NN;
    int*   chunks = offs + NN;
    int*   rank   = chunks + 128;
    int*   esrc   = rank + EE;
    unsigned short* xb = (unsigned short*)(esrc + EE);   // NN*DD bf16 = 19.2 MB

    k_scores<<<(NN * HH + 255) / 256, 256, 0, stream>>>(x, wsrc, wtrg, s_src, s_trg, counts, xb);
    k_hist<<<(EE + 255) / 256, 256, 0, stream>>>(ei, counts, rank);
    k_chunks<<<NBLK_SCAN, 256, 0, stream>>>(counts, chunks);
    k_scan<<<NBLK_SCAN, 256, 0, stream>>>(counts, chunks, offs);
    k_scatter<<<(EE + 255) / 256, 256, 0, stream>>>(ei, offs, rank, esrc);
    k_aggout<<<(NN + 63) / 64, 768, 0, stream>>>(x, xb, s_src, s_trg, offs, counts, esrc, lnw, wprj, out);
}